// Round 3
// baseline (438.205 us; speedup 1.0000x reference)
//
#include <hip/hip_runtime.h>
#include <stdint.h>

#define AS1 __attribute__((address_space(1)))
#define AS3 __attribute__((address_space(3)))

typedef __bf16 bf16x8 __attribute__((ext_vector_type(8)));
typedef float  f32x4  __attribute__((ext_vector_type(4)));

// ---------------------------------------------------------------- cast f32 -> bf16, 8 elems/thread
__global__ __launch_bounds__(256) void cast_bf16(const float* __restrict__ in,
                                                 __bf16* __restrict__ out, int n8) {
    int i = blockIdx.x * 256 + threadIdx.x;
    if (i >= n8) return;
    const float4* p = (const float4*)in + (size_t)i * 2;
    float4 x = p[0], y = p[1];
    bf16x8 v;
    v[0] = (__bf16)x.x; v[1] = (__bf16)x.y; v[2] = (__bf16)x.z; v[3] = (__bf16)x.w;
    v[4] = (__bf16)y.x; v[5] = (__bf16)y.y; v[6] = (__bf16)y.z; v[7] = (__bf16)y.w;
    *((bf16x8*)out + i) = v;
}

// ---------------------------------------------------------------- qb2[b][a] = q[b]·Wq[a] + bias[a] + conv_b[a]
// one wave per (b,a) dot; grid = 32*1024/4 blocks of 256 threads
__global__ __launch_bounds__(256) void prep_qb2(const float* __restrict__ q,
                                                const float* __restrict__ Wq,
                                                const float* __restrict__ bias,
                                                const float* __restrict__ convb,
                                                float* __restrict__ qb2) {
    int gw   = blockIdx.x * 4 + (threadIdx.x >> 6);
    int lane = threadIdx.x & 63;
    int b = gw >> 10, a = gw & 1023;
    const float* qr = q  + (size_t)b * 1024;
    const float* wr = Wq + (size_t)a * 1024;
    float s = 0.f;
#pragma unroll
    for (int j = 0; j < 16; ++j) s += qr[lane + 64 * j] * wr[lane + 64 * j];
    for (int m = 1; m < 64; m <<= 1) s += __shfl_xor(s, m);
    if (lane == 0) qb2[gw] = s + bias[a] + convb[a];
}

// ---------------------------------------------------------------- fused GEMM + loc-conv + tanh + fc reduce
// C_tile = value_chunk(128xK) @ Wv^T(128xK)  -> epilogue -> atomicAdd partial energies
// m97 structure: 128x128 tile, BK=64, 4 waves (2x2), 16x16x32 bf16 MFMA, global_load_lds w=16
__global__ __launch_bounds__(256) void gemm_fused(
    const __bf16* __restrict__ Abf,   // [8192][1024] bf16 chunk of value
    const __bf16* __restrict__ Bbf,   // [1024][1024] bf16 Wv
    const float*  __restrict__ qb2,   // [32][1024]  q·Wq + bias + conv_b
    const float*  __restrict__ la,    // [32][2048]  last_attn
    const float*  __restrict__ convw, // [1024][3]
    const float*  __restrict__ fcw,   // [1024]
    float* __restrict__ energy,       // [32][2048]
    int rowBase0)                     // chunk * 8192
{
    constexpr int K = 1024;
    __shared__ __bf16 As[128 * 64];
    __shared__ __bf16 Bs[128 * 64];

    const int tid  = threadIdx.x;
    const int lane = tid & 63;
    const int wid  = tid >> 6;
    const int wr   = wid >> 1, wc = wid & 1;
    const int rowBase = blockIdx.x * 128;   // within chunk
    const int colBase = blockIdx.y * 128;   // A-dim

    f32x4 acc[4][4] = {};

    for (int k0 = 0; k0 < K; k0 += 64) {
        // stage A-tile (128x64) and B-tile (128x64): 4 issues each, 16B/lane
#pragma unroll
        for (int is = 0; is < 4; ++is) {
            int idx16 = is * 256 + tid;        // 0..1023 16B-chunks
            int r = idx16 >> 3, s = idx16 & 7; // row, 16B segment within 128B row
            const __bf16* ga = Abf + (size_t)(rowBase + r) * K + k0 + s * 8;
            __builtin_amdgcn_global_load_lds((AS1 void*)ga, (AS3 void*)(As + idx16 * 8), 16, 0, 0);
            const __bf16* gb = Bbf + (size_t)(colBase + r) * K + k0 + s * 8;
            __builtin_amdgcn_global_load_lds((AS1 void*)gb, (AS3 void*)(Bs + idx16 * 8), 16, 0, 0);
        }
        __syncthreads();   // drains vmcnt for global_load_lds
#pragma unroll
        for (int kk = 0; kk < 2; ++kk) {
            bf16x8 af[4], bfr[4];
#pragma unroll
            for (int mi = 0; mi < 4; ++mi) {
                int row = wr * 64 + mi * 16 + (lane & 15);
                af[mi] = *(const bf16x8*)(As + row * 64 + kk * 32 + (lane >> 4) * 8);
            }
#pragma unroll
            for (int ni = 0; ni < 4; ++ni) {
                int row = wc * 64 + ni * 16 + (lane & 15);
                bfr[ni] = *(const bf16x8*)(Bs + row * 64 + kk * 32 + (lane >> 4) * 8);
            }
#pragma unroll
            for (int mi = 0; mi < 4; ++mi)
#pragma unroll
                for (int ni = 0; ni < 4; ++ni)
                    acc[mi][ni] = __builtin_amdgcn_mfma_f32_16x16x32_bf16(
                        af[mi], bfr[ni], acc[mi][ni], 0, 0, 0);
        }
        __syncthreads();
    }

    // -------- fused epilogue --------
    const int rGlobal0 = rowBase0 + rowBase;     // global flattened (b,t) row of tile
    const int b     = rGlobal0 >> 11;            // uniform: 2048 % 128 == 0
    const int tTile = rGlobal0 & 2047;
    const float* lab  = la  + (size_t)b * 2048;
    const float* qrow = qb2 + (size_t)b * 1024;

    float cw0[4], cw1[4], cw2[4], fv[4], qv[4];
#pragma unroll
    for (int ni = 0; ni < 4; ++ni) {
        int a = colBase + wc * 64 + ni * 16 + (lane & 15);
        cw0[ni] = convw[a * 3 + 0];
        cw1[ni] = convw[a * 3 + 1];
        cw2[ni] = convw[a * 3 + 2];
        fv[ni]  = fcw[a];
        qv[ni]  = qrow[a];
    }
    const int g4 = (lane >> 4) * 4;
#pragma unroll
    for (int mi = 0; mi < 4; ++mi) {
#pragma unroll
        for (int j = 0; j < 4; ++j) {
            int t = tTile + wr * 64 + mi * 16 + g4 + j;   // t within this b, [0,2048)
            float p1 = lab[t];
            float p0 = (t > 0)    ? lab[t - 1] : 0.f;     // SAME pad, per-b boundaries
            float p2 = (t < 2047) ? lab[t + 1] : 0.f;
            float sum = 0.f;
#pragma unroll
            for (int ni = 0; ni < 4; ++ni) {
                float e = acc[mi][ni][j] + qv[ni] + cw0[ni] * p0 + cw1[ni] * p1 + cw2[ni] * p2;
                // tanh(x) = 1 - 2/(1+e^{2x}); saturates correctly at +/-inf
                float h = 1.f - 2.f / (1.f + __expf(2.f * e));
                sum += fv[ni] * h;
            }
            // reduce over the 16 column-lanes (same output row)
            sum += __shfl_xor(sum, 1);
            sum += __shfl_xor(sum, 2);
            sum += __shfl_xor(sum, 4);
            sum += __shfl_xor(sum, 8);
            if ((lane & 15) == 0)
                atomicAdd(&energy[b * 2048 + t], sum);
        }
    }
}

// ---------------------------------------------------------------- softmax over T per batch row
__global__ __launch_bounds__(256) void softmax_rows(const float* __restrict__ energy,
                                                    float* __restrict__ attn) {
    int b = blockIdx.x, tid = threadIdx.x;
    const float* e = energy + (size_t)b * 2048;
    float* o = attn + (size_t)b * 2048;
    __shared__ float red[4], red2[4];

    float m = -1e30f;
#pragma unroll
    for (int k = 0; k < 8; ++k) m = fmaxf(m, e[tid + 256 * k]);
    for (int s = 1; s < 64; s <<= 1) m = fmaxf(m, __shfl_xor(m, s));
    if ((tid & 63) == 0) red[tid >> 6] = m;
    __syncthreads();
    m = fmaxf(fmaxf(red[0], red[1]), fmaxf(red[2], red[3]));

    float s = 0.f, vals[8];
#pragma unroll
    for (int k = 0; k < 8; ++k) { vals[k] = __expf(e[tid + 256 * k] - m); s += vals[k]; }
    for (int t = 1; t < 64; t <<= 1) s += __shfl_xor(s, t);
    if ((tid & 63) == 0) red2[tid >> 6] = s;
    __syncthreads();
    s = red2[0] + red2[1] + red2[2] + red2[3];
    float inv = 1.f / s;
#pragma unroll
    for (int k = 0; k < 8; ++k) o[tid + 256 * k] = vals[k] * inv;
}

// ---------------------------------------------------------------- context[b][d] = sum_t attn[b][t]*value[b][t][d]
// grid (32, 16): block = one b, 128 t's, all 1024 d (float4/thread); atomic accumulate
__global__ __launch_bounds__(256) void context_kernel(const float* __restrict__ attn,
                                                      const float* __restrict__ value,
                                                      float* __restrict__ ctx) {
    int b = blockIdx.x, tc = blockIdx.y, tid = threadIdx.x;
    const float*  ab = attn + (size_t)b * 2048 + tc * 128;
    const float4* vb = (const float4*)value + ((size_t)b * 2048 + tc * 128) * 256 + tid;
    float4 c = {0.f, 0.f, 0.f, 0.f};
#pragma unroll 8
    for (int t = 0; t < 128; ++t) {
        float  w = ab[t];
        float4 v = vb[(size_t)t * 256];
        c.x += w * v.x; c.y += w * v.y; c.z += w * v.z; c.w += w * v.w;
    }
    float* out = ctx + (size_t)b * 1024 + tid * 4;
    atomicAdd(out + 0, c.x);
    atomicAdd(out + 1, c.y);
    atomicAdd(out + 2, c.z);
    atomicAdd(out + 3, c.w);
}

// ================================================================ host
extern "C" void kernel_launch(void* const* d_in, const int* in_sizes, int n_in,
                              void* d_out, int out_size, void* d_ws, size_t ws_size,
                              hipStream_t stream) {
    const float* query     = (const float*)d_in[0];
    const float* value     = (const float*)d_in[1];
    const float* last_attn = (const float*)d_in[2];
    const float* conv_w    = (const float*)d_in[3];
    const float* conv_b    = (const float*)d_in[4];
    const float* Wq        = (const float*)d_in[5];
    const float* Wv        = (const float*)d_in[6];
    const float* bias      = (const float*)d_in[7];
    const float* fc_w      = (const float*)d_in[8];
    // fc_b (d_in[9]) cancels in softmax

    float* ctx  = (float*)d_out;            // [32][1024]
    float* attn = (float*)d_out + 32 * 1024; // [32][2048]

    // workspace layout
    const size_t VBF_B  = (size_t)8192 * 1024 * 2;  // 16 MB chunk of value in bf16
    const size_t WVBF_B = (size_t)1024 * 1024 * 2;  //  2 MB
    const size_t QB2_B  = (size_t)32 * 1024 * 4;
    const size_t EN_B   = (size_t)32 * 2048 * 4;
    if (ws_size < VBF_B + WVBF_B + QB2_B + EN_B) return;  // loud failure, no OOB

    char*   ws     = (char*)d_ws;
    __bf16* vbf    = (__bf16*)ws;
    __bf16* wvbf   = (__bf16*)(ws + VBF_B);
    float*  qb2    = (float*)(ws + VBF_B + WVBF_B);
    float*  energy = (float*)(ws + VBF_B + WVBF_B + QB2_B);

    hipMemsetAsync(energy, 0, EN_B, stream);
    hipMemsetAsync(ctx, 0, 32 * 1024 * sizeof(float), stream);

    cast_bf16<<<512, 256, 0, stream>>>(Wv, wvbf, 1024 * 1024 / 8);
    prep_qb2<<<8192, 256, 0, stream>>>(query, Wq, bias, conv_b, qb2);

    for (int c = 0; c < 8; ++c) {
        const float* vchunk = value + (size_t)c * 8192 * 1024;
        cast_bf16<<<4096, 256, 0, stream>>>(vchunk, vbf, 8192 * 1024 / 8);
        dim3 g(64, 8);
        gemm_fused<<<g, 256, 0, stream>>>(vbf, wvbf, qb2, last_attn, conv_w, fc_w,
                                          energy, c * 8192);
    }

    softmax_rows<<<32, 256, 0, stream>>>(energy, attn);
    dim3 gc(32, 16);
    context_kernel<<<gc, 256, 0, stream>>>(attn, value, ctx);
}

// Round 4
// 412.005 us; speedup vs baseline: 1.0636x; 1.0636x over previous
//
#include <hip/hip_runtime.h>
#include <stdint.h>

#define AS1 __attribute__((address_space(1)))
#define AS3 __attribute__((address_space(3)))

typedef __bf16 bf16x8 __attribute__((ext_vector_type(8)));
typedef float  f32x4  __attribute__((ext_vector_type(4)));

// ---------------------------------------------------------------- cast f32 -> bf16, 8 elems/thread
__global__ __launch_bounds__(256) void cast_bf16(const float* __restrict__ in,
                                                 __bf16* __restrict__ out, int n8) {
    int i = blockIdx.x * 256 + threadIdx.x;
    if (i >= n8) return;
    const float4* p = (const float4*)in + (size_t)i * 2;
    float4 x = p[0], y = p[1];
    bf16x8 v;
    v[0] = (__bf16)x.x; v[1] = (__bf16)x.y; v[2] = (__bf16)x.z; v[3] = (__bf16)x.w;
    v[4] = (__bf16)y.x; v[5] = (__bf16)y.y; v[6] = (__bf16)y.z; v[7] = (__bf16)y.w;
    *((bf16x8*)out + i) = v;
}

// ---------------------------------------------------------------- qb2[b][a] = q[b]·Wq[a] + bias[a] + conv_b[a]
// one wave per a, loops all 32 b's; Wq row read ONCE into registers (4 MB total Wq traffic)
__global__ __launch_bounds__(256) void prep_qb2(const float* __restrict__ q,
                                                const float* __restrict__ Wq,
                                                const float* __restrict__ bias,
                                                const float* __restrict__ convb,
                                                float* __restrict__ qb2) {
    int wid  = threadIdx.x >> 6;
    int lane = threadIdx.x & 63;
    int a    = blockIdx.x * 4 + wid;            // grid 256 blocks -> a in [0,1024)
    const float* wr_ = Wq + (size_t)a * 1024;
    float w[16];
#pragma unroll
    for (int j = 0; j < 16; ++j) w[j] = wr_[lane + 64 * j];
    float bb = bias[a] + convb[a];
    for (int b = 0; b < 32; ++b) {
        const float* qr = q + (size_t)b * 1024;
        float s = 0.f;
#pragma unroll
        for (int j = 0; j < 16; ++j) s += w[j] * qr[lane + 64 * j];
        for (int m = 1; m < 64; m <<= 1) s += __shfl_xor(s, m);
        if (lane == 0) qb2[b * 1024 + a] = s + bb;
    }
}

// ---------------------------------------------------------------- fused GEMM + loc-conv + tanh + fc reduce
// single launch over all of value: grid (512 row-tiles, 8 col-tiles), 128x128 tile, BK=64,
// 4 waves (2x2), 16x16x32 bf16 MFMA, global_load_lds w=16. Partial energies per col-tile
// written via LDS gather + coalesced store (no atomics).
__global__ __launch_bounds__(256) void gemm_fused(
    const __bf16* __restrict__ Abf,   // [65536][1024] bf16 value
    const __bf16* __restrict__ Bbf,   // [1024][1024] bf16 Wv
    const float*  __restrict__ qb2,   // [32][1024]  q·Wq + bias + conv_b
    const float*  __restrict__ la,    // [32][2048]  last_attn
    const float*  __restrict__ convw, // [1024][3]
    const float*  __restrict__ fcw,   // [1024]
    float* __restrict__ ep)           // [8][32][2048] partial energies per col-tile
{
    constexpr int K = 1024;
    __shared__ __bf16 As[128 * 64];
    __shared__ __bf16 Bs[128 * 64];
    __shared__ float  ep_s[128][2];

    const int tid  = threadIdx.x;
    const int lane = tid & 63;
    const int wid  = tid >> 6;
    const int wr   = wid >> 1, wc = wid & 1;
    const int rowBase = blockIdx.x * 128;   // global flattened (b,t) row
    const int ct      = blockIdx.y;         // col tile
    const int colBase = ct * 128;

    f32x4 acc[4][4] = {};

    for (int k0 = 0; k0 < K; k0 += 64) {
#pragma unroll
        for (int is = 0; is < 4; ++is) {
            int idx16 = is * 256 + tid;        // 0..1023 16B-chunks
            int r = idx16 >> 3, s = idx16 & 7; // row, 16B segment within 128B row
            const __bf16* ga = Abf + (size_t)(rowBase + r) * K + k0 + s * 8;
            __builtin_amdgcn_global_load_lds((AS1 void*)ga, (AS3 void*)(As + idx16 * 8), 16, 0, 0);
            const __bf16* gb = Bbf + (size_t)(colBase + r) * K + k0 + s * 8;
            __builtin_amdgcn_global_load_lds((AS1 void*)gb, (AS3 void*)(Bs + idx16 * 8), 16, 0, 0);
        }
        __syncthreads();   // drains vmcnt for global_load_lds
#pragma unroll
        for (int kk = 0; kk < 2; ++kk) {
            bf16x8 af[4], bfr[4];
#pragma unroll
            for (int mi = 0; mi < 4; ++mi) {
                int row = wr * 64 + mi * 16 + (lane & 15);
                af[mi] = *(const bf16x8*)(As + row * 64 + kk * 32 + (lane >> 4) * 8);
            }
#pragma unroll
            for (int ni = 0; ni < 4; ++ni) {
                int row = wc * 64 + ni * 16 + (lane & 15);
                bfr[ni] = *(const bf16x8*)(Bs + row * 64 + kk * 32 + (lane >> 4) * 8);
            }
#pragma unroll
            for (int mi = 0; mi < 4; ++mi)
#pragma unroll
                for (int ni = 0; ni < 4; ++ni)
                    acc[mi][ni] = __builtin_amdgcn_mfma_f32_16x16x32_bf16(
                        af[mi], bfr[ni], acc[mi][ni], 0, 0, 0);
        }
        __syncthreads();
    }

    // -------- fused epilogue --------
    const int b    = rowBase >> 11;            // uniform: 2048 % 128 == 0
    const int tTile = rowBase & 2047;
    const float* lab  = la  + (size_t)b * 2048;
    const float* qrow = qb2 + (size_t)b * 1024;

    float cw0[4], cw1[4], cw2[4], fv[4], qv[4];
#pragma unroll
    for (int ni = 0; ni < 4; ++ni) {
        int a = colBase + wc * 64 + ni * 16 + (lane & 15);
        cw0[ni] = convw[a * 3 + 0];
        cw1[ni] = convw[a * 3 + 1];
        cw2[ni] = convw[a * 3 + 2];
        fv[ni]  = fcw[a];
        qv[ni]  = qrow[a];
    }
    const int g4 = (lane >> 4) * 4;
#pragma unroll
    for (int mi = 0; mi < 4; ++mi) {
#pragma unroll
        for (int j = 0; j < 4; ++j) {
            int t = tTile + wr * 64 + mi * 16 + g4 + j;   // t within this b, [0,2048)
            float p1 = lab[t];
            float p0 = (t > 0)    ? lab[t - 1] : 0.f;     // SAME pad, per-b boundaries
            float p2 = (t < 2047) ? lab[t + 1] : 0.f;
            float sum = 0.f;
#pragma unroll
            for (int ni = 0; ni < 4; ++ni) {
                float e = acc[mi][ni][j] + qv[ni] + cw0[ni] * p0 + cw1[ni] * p1 + cw2[ni] * p2;
                // tanh(x) = 1 - 2/(1+e^{2x}); saturates correctly at +/-inf
                float h = 1.f - 2.f / (1.f + __expf(2.f * e));
                sum += fv[ni] * h;
            }
            // reduce over the 16 column-lanes (same output row)
            sum += __shfl_xor(sum, 1);
            sum += __shfl_xor(sum, 2);
            sum += __shfl_xor(sum, 4);
            sum += __shfl_xor(sum, 8);
            if ((lane & 15) == 0)
                ep_s[wr * 64 + mi * 16 + g4 + j][wc] = sum;
        }
    }
    __syncthreads();
    if (tid < 128) {
        float e = ep_s[tid][0] + ep_s[tid][1];
        ep[(size_t)ct * 65536 + rowBase + tid] = e;   // rowBase+tid == b*2048 + t
    }
}

// ---------------------------------------------------------------- softmax over T per batch row (sums 8 col-tile partials)
__global__ __launch_bounds__(256) void softmax_rows(const float* __restrict__ ep,
                                                    float* __restrict__ attn) {
    int b = blockIdx.x, tid = threadIdx.x;
    float* o = attn + (size_t)b * 2048;
    __shared__ float red[4], red2[4];

    float e8[8];
#pragma unroll
    for (int k = 0; k < 8; ++k) {
        int t = tid + 256 * k;
        float s = 0.f;
#pragma unroll
        for (int ct = 0; ct < 8; ++ct) s += ep[(size_t)ct * 65536 + b * 2048 + t];
        e8[k] = s;
    }

    float m = -1e30f;
#pragma unroll
    for (int k = 0; k < 8; ++k) m = fmaxf(m, e8[k]);
    for (int s = 1; s < 64; s <<= 1) m = fmaxf(m, __shfl_xor(m, s));
    if ((tid & 63) == 0) red[tid >> 6] = m;
    __syncthreads();
    m = fmaxf(fmaxf(red[0], red[1]), fmaxf(red[2], red[3]));

    float s = 0.f, vals[8];
#pragma unroll
    for (int k = 0; k < 8; ++k) { vals[k] = __expf(e8[k] - m); s += vals[k]; }
    for (int t = 1; t < 64; t <<= 1) s += __shfl_xor(s, t);
    if ((tid & 63) == 0) red2[tid >> 6] = s;
    __syncthreads();
    s = red2[0] + red2[1] + red2[2] + red2[3];
    float inv = 1.f / s;
#pragma unroll
    for (int k = 0; k < 8; ++k) o[tid + 256 * k] = vals[k] * inv;
}

// ---------------------------------------------------------------- context[b][d] = sum_t attn[b][t]*value[b][t][d]
// reads the bf16 copy of value (half the traffic); grid (32, 8); 256 t's per block
__global__ __launch_bounds__(256) void context_kernel(const float* __restrict__ attn,
                                                      const __bf16* __restrict__ vbf,
                                                      float* __restrict__ ctx) {
    int b = blockIdx.x, tc = blockIdx.y, tid = threadIdx.x;
    int half = tid >> 7, dc = tid & 127;          // dc*8 .. dc*8+7 of D
    const float*  ab = attn + (size_t)b * 2048 + tc * 256 + half * 128;
    const __bf16* vb = vbf + ((size_t)(b * 2048 + tc * 256 + half * 128)) * 1024 + dc * 8;
    float c[8] = {};
#pragma unroll 4
    for (int t = 0; t < 128; ++t) {
        float  w = ab[t];
        bf16x8 v = *(const bf16x8*)(vb + (size_t)t * 1024);
#pragma unroll
        for (int k = 0; k < 8; ++k) c[k] += w * (float)v[k];
    }
    float* out = ctx + (size_t)b * 1024 + dc * 8;
#pragma unroll
    for (int k = 0; k < 8; ++k) atomicAdd(out + k, c[k]);
}

// ================================================================ host
extern "C" void kernel_launch(void* const* d_in, const int* in_sizes, int n_in,
                              void* d_out, int out_size, void* d_ws, size_t ws_size,
                              hipStream_t stream) {
    const float* query     = (const float*)d_in[0];
    const float* value     = (const float*)d_in[1];
    const float* last_attn = (const float*)d_in[2];
    const float* conv_w    = (const float*)d_in[3];
    const float* conv_b    = (const float*)d_in[4];
    const float* Wq        = (const float*)d_in[5];
    const float* Wv        = (const float*)d_in[6];
    const float* bias      = (const float*)d_in[7];
    const float* fc_w      = (const float*)d_in[8];
    // fc_b (d_in[9]) cancels in softmax

    float* ctx  = (float*)d_out;             // [32][1024]
    float* attn = (float*)d_out + 32 * 1024; // [32][2048]

    // workspace layout (ws is 1 GiB per harness poison)
    const size_t VBF_B  = (size_t)65536 * 1024 * 2;  // 128 MB full value in bf16
    const size_t WVBF_B = (size_t)1024 * 1024 * 2;   //   2 MB
    const size_t QB2_B  = (size_t)32 * 1024 * 4;     // 128 KB
    const size_t EP_B   = (size_t)8 * 32 * 2048 * 4; //   2 MB partial energies
    if (ws_size < VBF_B + WVBF_B + QB2_B + EP_B) return;  // loud failure, no OOB

    char*   ws   = (char*)d_ws;
    __bf16* vbf  = (__bf16*)ws;
    __bf16* wvbf = (__bf16*)(ws + VBF_B);
    float*  qb2  = (float*)(ws + VBF_B + WVBF_B);
    float*  ep   = (float*)(ws + VBF_B + WVBF_B + QB2_B);

    hipMemsetAsync(ctx, 0, 32 * 1024 * sizeof(float), stream);

    cast_bf16<<<512, 256, 0, stream>>>(Wv, wvbf, 1024 * 1024 / 8);
    prep_qb2<<<256, 256, 0, stream>>>(query, Wq, bias, conv_b, qb2);
    cast_bf16<<<32768, 256, 0, stream>>>(value, vbf, 65536 * 1024 / 8);

    dim3 g(512, 8);
    gemm_fused<<<g, 256, 0, stream>>>(vbf, wvbf, qb2, last_attn, conv_w, fc_w, ep);

    softmax_rows<<<32, 256, 0, stream>>>(ep, attn);
    dim3 gc(32, 8);
    context_kernel<<<gc, 256, 0, stream>>>(attn, vbf, ctx);
}

// Round 5
// 405.850 us; speedup vs baseline: 1.0797x; 1.0152x over previous
//
#include <hip/hip_runtime.h>
#include <stdint.h>

#define AS1 __attribute__((address_space(1)))
#define AS3 __attribute__((address_space(3)))

typedef __bf16 bf16x8 __attribute__((ext_vector_type(8)));
typedef float  f32x4  __attribute__((ext_vector_type(4)));

// ---------------------------------------------------------------- cast f32 -> bf16, 8 elems/thread
__global__ __launch_bounds__(256) void cast_bf16(const float* __restrict__ in,
                                                 __bf16* __restrict__ out, int n8) {
    int i = blockIdx.x * 256 + threadIdx.x;
    if (i >= n8) return;
    const float4* p = (const float4*)in + (size_t)i * 2;
    float4 x = p[0], y = p[1];
    bf16x8 v;
    v[0] = (__bf16)x.x; v[1] = (__bf16)x.y; v[2] = (__bf16)x.z; v[3] = (__bf16)x.w;
    v[4] = (__bf16)y.x; v[5] = (__bf16)y.y; v[6] = (__bf16)y.z; v[7] = (__bf16)y.w;
    *((bf16x8*)out + i) = v;
}

// ---------------------------------------------------------------- qb2[b][a] = q[b]·Wq[a] + bias[a] + conv_b[a]
// one wave per a, loops all 32 b's; Wq row read ONCE into registers (4 MB total Wq traffic)
__global__ __launch_bounds__(256) void prep_qb2(const float* __restrict__ q,
                                                const float* __restrict__ Wq,
                                                const float* __restrict__ bias,
                                                const float* __restrict__ convb,
                                                float* __restrict__ qb2) {
    int wid  = threadIdx.x >> 6;
    int lane = threadIdx.x & 63;
    int a    = blockIdx.x * 4 + wid;            // grid 256 blocks -> a in [0,1024)
    const float* wr_ = Wq + (size_t)a * 1024;
    float w[16];
#pragma unroll
    for (int j = 0; j < 16; ++j) w[j] = wr_[lane + 64 * j];
    float bb = bias[a] + convb[a];
    for (int b = 0; b < 32; ++b) {
        const float* qr = q + (size_t)b * 1024;
        float s = 0.f;
#pragma unroll
        for (int j = 0; j < 16; ++j) s += w[j] * qr[lane + 64 * j];
        for (int m = 1; m < 64; m <<= 1) s += __shfl_xor(s, m);
        if (lane == 0) qb2[b * 1024 + a] = s + bb;
    }
}

// ---------------------------------------------------------------- fused GEMM + loc-conv + tanh + fc reduce
// 1-D grid of 4096 blocks. Logical work: swz -> (rt = swz>>3, ct = swz&7) so the 8 blocks
// sharing one A row-panel are dispatch-adjacent; chunked XCD swizzle (T1, nwg%8==0) keeps
// each XCD's chunk L2-resident (its A-panel run + the whole 2 MB B).
// 128x128 tile, BK=64, 4 waves (2x2), 16x16x32 bf16 MFMA, global_load_lds w=16.
__global__ __launch_bounds__(256) void gemm_fused(
    const __bf16* __restrict__ Abf,   // [65536][1024] bf16 value
    const __bf16* __restrict__ Bbf,   // [1024][1024] bf16 Wv
    const float*  __restrict__ qb2,   // [32][1024]  q·Wq + bias + conv_b
    const float*  __restrict__ la,    // [32][2048]  last_attn
    const float*  __restrict__ convw, // [1024][3]
    const float*  __restrict__ fcw,   // [1024]
    float* __restrict__ ep)           // [8][32][2048] partial energies per col-tile
{
    constexpr int K = 1024;
    __shared__ __bf16 As[128 * 64];
    __shared__ __bf16 Bs[128 * 64];
    __shared__ float  ep_s[128][2];

    const int tid  = threadIdx.x;
    const int lane = tid & 63;
    const int wid  = tid >> 6;
    const int wr   = wid >> 1, wc = wid & 1;

    // T1 chunked XCD swizzle: bid%8 is the HW XCD; give each XCD a contiguous logical chunk.
    const int bid = blockIdx.x;                       // 0..4095 (nwg = 4096, %8 == 0)
    const int swz = (bid & 7) * 512 + (bid >> 3);     // logical work id
    const int rt  = swz >> 3;                         // row tile 0..511
    const int ct  = swz & 7;                          // col tile 0..7
    const int rowBase = rt * 128;                     // global flattened (b,t) row
    const int colBase = ct * 128;

    f32x4 acc[4][4] = {};

    for (int k0 = 0; k0 < K; k0 += 64) {
#pragma unroll
        for (int is = 0; is < 4; ++is) {
            int idx16 = is * 256 + tid;        // 0..1023 16B-chunks
            int r = idx16 >> 3, s = idx16 & 7; // row, 16B segment within 128B row
            const __bf16* ga = Abf + (size_t)(rowBase + r) * K + k0 + s * 8;
            __builtin_amdgcn_global_load_lds((AS1 void*)ga, (AS3 void*)(As + idx16 * 8), 16, 0, 0);
            const __bf16* gb = Bbf + (size_t)(colBase + r) * K + k0 + s * 8;
            __builtin_amdgcn_global_load_lds((AS1 void*)gb, (AS3 void*)(Bs + idx16 * 8), 16, 0, 0);
        }
        __syncthreads();   // drains vmcnt for global_load_lds
#pragma unroll
        for (int kk = 0; kk < 2; ++kk) {
            bf16x8 af[4], bfr[4];
#pragma unroll
            for (int mi = 0; mi < 4; ++mi) {
                int row = wr * 64 + mi * 16 + (lane & 15);
                af[mi] = *(const bf16x8*)(As + row * 64 + kk * 32 + (lane >> 4) * 8);
            }
#pragma unroll
            for (int ni = 0; ni < 4; ++ni) {
                int row = wc * 64 + ni * 16 + (lane & 15);
                bfr[ni] = *(const bf16x8*)(Bs + row * 64 + kk * 32 + (lane >> 4) * 8);
            }
#pragma unroll
            for (int mi = 0; mi < 4; ++mi)
#pragma unroll
                for (int ni = 0; ni < 4; ++ni)
                    acc[mi][ni] = __builtin_amdgcn_mfma_f32_16x16x32_bf16(
                        af[mi], bfr[ni], acc[mi][ni], 0, 0, 0);
        }
        __syncthreads();
    }

    // -------- fused epilogue --------
    const int b     = rowBase >> 11;            // uniform: 2048 % 128 == 0
    const int tTile = rowBase & 2047;
    const float* lab  = la  + (size_t)b * 2048;
    const float* qrow = qb2 + (size_t)b * 1024;

    float cw0[4], cw1[4], cw2[4], fv[4], qv[4];
#pragma unroll
    for (int ni = 0; ni < 4; ++ni) {
        int a = colBase + wc * 64 + ni * 16 + (lane & 15);
        cw0[ni] = convw[a * 3 + 0];
        cw1[ni] = convw[a * 3 + 1];
        cw2[ni] = convw[a * 3 + 2];
        fv[ni]  = fcw[a];
        qv[ni]  = qrow[a];
    }
    const int g4 = (lane >> 4) * 4;
#pragma unroll
    for (int mi = 0; mi < 4; ++mi) {
#pragma unroll
        for (int j = 0; j < 4; ++j) {
            int t = tTile + wr * 64 + mi * 16 + g4 + j;   // t within this b, [0,2048)
            float p1 = lab[t];
            float p0 = (t > 0)    ? lab[t - 1] : 0.f;     // SAME pad, per-b boundaries
            float p2 = (t < 2047) ? lab[t + 1] : 0.f;
            float sum = 0.f;
#pragma unroll
            for (int ni = 0; ni < 4; ++ni) {
                float e = acc[mi][ni][j] + qv[ni] + cw0[ni] * p0 + cw1[ni] * p1 + cw2[ni] * p2;
                // tanh(x) = 1 - 2/(1+e^{2x}); saturates correctly at +/-inf
                float h = 1.f - 2.f / (1.f + __expf(2.f * e));
                sum += fv[ni] * h;
            }
            // reduce over the 16 column-lanes (same output row)
            sum += __shfl_xor(sum, 1);
            sum += __shfl_xor(sum, 2);
            sum += __shfl_xor(sum, 4);
            sum += __shfl_xor(sum, 8);
            if ((lane & 15) == 0)
                ep_s[wr * 64 + mi * 16 + g4 + j][wc] = sum;
        }
    }
    __syncthreads();
    if (tid < 128) {
        float e = ep_s[tid][0] + ep_s[tid][1];
        ep[(size_t)ct * 65536 + rowBase + tid] = e;   // rowBase+tid == b*2048 + t
    }
}

// ---------------------------------------------------------------- softmax over T per batch row (sums 8 col-tile partials)
__global__ __launch_bounds__(256) void softmax_rows(const float* __restrict__ ep,
                                                    float* __restrict__ attn) {
    int b = blockIdx.x, tid = threadIdx.x;
    float* o = attn + (size_t)b * 2048;
    __shared__ float red[4], red2[4];

    float e8[8];
#pragma unroll
    for (int k = 0; k < 8; ++k) {
        int t = tid + 256 * k;
        float s = 0.f;
#pragma unroll
        for (int ct = 0; ct < 8; ++ct) s += ep[(size_t)ct * 65536 + b * 2048 + t];
        e8[k] = s;
    }

    float m = -1e30f;
#pragma unroll
    for (int k = 0; k < 8; ++k) m = fmaxf(m, e8[k]);
    for (int s = 1; s < 64; s <<= 1) m = fmaxf(m, __shfl_xor(m, s));
    if ((tid & 63) == 0) red[tid >> 6] = m;
    __syncthreads();
    m = fmaxf(fmaxf(red[0], red[1]), fmaxf(red[2], red[3]));

    float s = 0.f, vals[8];
#pragma unroll
    for (int k = 0; k < 8; ++k) { vals[k] = __expf(e8[k] - m); s += vals[k]; }
    for (int t = 1; t < 64; t <<= 1) s += __shfl_xor(s, t);
    if ((tid & 63) == 0) red2[tid >> 6] = s;
    __syncthreads();
    s = red2[0] + red2[1] + red2[2] + red2[3];
    float inv = 1.f / s;
#pragma unroll
    for (int k = 0; k < 8; ++k) o[tid + 256 * k] = vals[k] * inv;
}

// ---------------------------------------------------------------- context[b][d] = sum_t attn[b][t]*value[b][t][d]
// reads the bf16 copy of value (half the traffic); grid (32, 8); 256 t's per block
__global__ __launch_bounds__(256) void context_kernel(const float* __restrict__ attn,
                                                      const __bf16* __restrict__ vbf,
                                                      float* __restrict__ ctx) {
    int b = blockIdx.x, tc = blockIdx.y, tid = threadIdx.x;
    int half = tid >> 7, dc = tid & 127;          // dc*8 .. dc*8+7 of D
    const float*  ab = attn + (size_t)b * 2048 + tc * 256 + half * 128;
    const __bf16* vb = vbf + ((size_t)(b * 2048 + tc * 256 + half * 128)) * 1024 + dc * 8;
    float c[8] = {};
#pragma unroll 4
    for (int t = 0; t < 128; ++t) {
        float  w = ab[t];
        bf16x8 v = *(const bf16x8*)(vb + (size_t)t * 1024);
#pragma unroll
        for (int k = 0; k < 8; ++k) c[k] += w * (float)v[k];
    }
    float* out = ctx + (size_t)b * 1024 + dc * 8;
#pragma unroll
    for (int k = 0; k < 8; ++k) atomicAdd(out + k, c[k]);
}

// ================================================================ host
extern "C" void kernel_launch(void* const* d_in, const int* in_sizes, int n_in,
                              void* d_out, int out_size, void* d_ws, size_t ws_size,
                              hipStream_t stream) {
    const float* query     = (const float*)d_in[0];
    const float* value     = (const float*)d_in[1];
    const float* last_attn = (const float*)d_in[2];
    const float* conv_w    = (const float*)d_in[3];
    const float* conv_b    = (const float*)d_in[4];
    const float* Wq        = (const float*)d_in[5];
    const float* Wv        = (const float*)d_in[6];
    const float* bias      = (const float*)d_in[7];
    const float* fc_w      = (const float*)d_in[8];
    // fc_b (d_in[9]) cancels in softmax

    float* ctx  = (float*)d_out;             // [32][1024]
    float* attn = (float*)d_out + 32 * 1024; // [32][2048]

    // workspace layout (ws is 1 GiB per harness poison)
    const size_t VBF_B  = (size_t)65536 * 1024 * 2;  // 128 MB full value in bf16
    const size_t WVBF_B = (size_t)1024 * 1024 * 2;   //   2 MB
    const size_t QB2_B  = (size_t)32 * 1024 * 4;     // 128 KB
    const size_t EP_B   = (size_t)8 * 32 * 2048 * 4; //   2 MB partial energies
    if (ws_size < VBF_B + WVBF_B + QB2_B + EP_B) return;  // loud failure, no OOB

    char*   ws   = (char*)d_ws;
    __bf16* vbf  = (__bf16*)ws;
    __bf16* wvbf = (__bf16*)(ws + VBF_B);
    float*  qb2  = (float*)(ws + VBF_B + WVBF_B);
    float*  ep   = (float*)(ws + VBF_B + WVBF_B + QB2_B);

    hipMemsetAsync(ctx, 0, 32 * 1024 * sizeof(float), stream);

    cast_bf16<<<512, 256, 0, stream>>>(Wv, wvbf, 1024 * 1024 / 8);
    prep_qb2<<<256, 256, 0, stream>>>(query, Wq, bias, conv_b, qb2);
    cast_bf16<<<32768, 256, 0, stream>>>(value, vbf, 65536 * 1024 / 8);

    gemm_fused<<<4096, 256, 0, stream>>>(vbf, wvbf, qb2, last_attn, conv_w, fc_w, ep);

    softmax_rows<<<32, 256, 0, stream>>>(ep, attn);
    dim3 gc(32, 8);
    context_kernel<<<gc, 256, 0, stream>>>(attn, vbf, ctx);
}

// Round 6
// 381.861 us; speedup vs baseline: 1.1476x; 1.0628x over previous
//
#include <hip/hip_runtime.h>
#include <stdint.h>

#define AS1 __attribute__((address_space(1)))
#define AS3 __attribute__((address_space(3)))

typedef __bf16 bf16x8 __attribute__((ext_vector_type(8)));
typedef float  f32x4  __attribute__((ext_vector_type(4)));

// ---------------------------------------------------------------- cast f32 -> bf16, 8 elems/thread
__global__ __launch_bounds__(256) void cast_bf16(const float* __restrict__ in,
                                                 __bf16* __restrict__ out, int n8) {
    int i = blockIdx.x * 256 + threadIdx.x;
    if (i >= n8) return;
    const float4* p = (const float4*)in + (size_t)i * 2;
    float4 x = p[0], y = p[1];
    bf16x8 v;
    v[0] = (__bf16)x.x; v[1] = (__bf16)x.y; v[2] = (__bf16)x.z; v[3] = (__bf16)x.w;
    v[4] = (__bf16)y.x; v[5] = (__bf16)y.y; v[6] = (__bf16)y.z; v[7] = (__bf16)y.w;
    *((bf16x8*)out + i) = v;
}

// ---------------------------------------------------------------- qb2[b][a] = q[b]·Wq[a] + bias[a] + conv_b[a]
__global__ __launch_bounds__(256) void prep_qb2(const float* __restrict__ q,
                                                const float* __restrict__ Wq,
                                                const float* __restrict__ bias,
                                                const float* __restrict__ convb,
                                                float* __restrict__ qb2) {
    int wid  = threadIdx.x >> 6;
    int lane = threadIdx.x & 63;
    int a    = blockIdx.x * 4 + wid;            // grid 256 blocks -> a in [0,1024)
    const float* wr_ = Wq + (size_t)a * 1024;
    float w[16];
#pragma unroll
    for (int j = 0; j < 16; ++j) w[j] = wr_[lane + 64 * j];
    float bb = bias[a] + convb[a];
    for (int b = 0; b < 32; ++b) {
        const float* qr = q + (size_t)b * 1024;
        float s = 0.f;
#pragma unroll
        for (int j = 0; j < 16; ++j) s += w[j] * qr[lane + 64 * j];
        for (int m = 1; m < 64; m <<= 1) s += __shfl_xor(s, m);
        if (lane == 0) qb2[b * 1024 + a] = s + bb;
    }
}

// ---------------------------------------------------------------- fused GEMM + loc-conv + tanh + fc reduce
// 128x128 tile, BK=64, 4 waves (2x2), 16x16x32 bf16 MFMA.
// R5 changes: (1) XOR-swizzled LDS (pre-swizzled GLOBAL source + swizzled ds_read slot,
// global_load_lds dest stays linear — rule #21 both-sides-or-neither); (2) LDS double
// buffer with next-tile stage ISSUED BEFORE compute (T3-minimum); (3) setprio around MFMA.
__global__ __launch_bounds__(256) void gemm_fused(
    const __bf16* __restrict__ Abf,   // [65536][1024] bf16 value
    const __bf16* __restrict__ Bbf,   // [1024][1024] bf16 Wv
    const float*  __restrict__ qb2,   // [32][1024]  q·Wq + bias + conv_b
    const float*  __restrict__ la,    // [32][2048]  last_attn
    const float*  __restrict__ convw, // [1024][3]
    const float*  __restrict__ fcw,   // [1024]
    float* __restrict__ ep)           // [8][32][2048] partial energies per col-tile
{
    constexpr int K = 1024;
    __shared__ __bf16 As[2][128 * 64];
    __shared__ __bf16 Bs[2][128 * 64];
    __shared__ float  ep_s[128][2];

    const int tid  = threadIdx.x;
    const int lane = tid & 63;
    const int wid  = tid >> 6;
    const int wr   = wid >> 1, wc = wid & 1;

    // T1 chunked XCD swizzle (nwg=4096, %8==0): adjacent logical ids share the A row-panel.
    const int bid = blockIdx.x;
    const int swz = (bid & 7) * 512 + (bid >> 3);
    const int rt  = swz >> 3;                         // row tile 0..511
    const int ct  = swz & 7;                          // col tile 0..7
    const int rowBase = rt * 128;
    const int colBase = ct * 128;

    f32x4 acc[4][4] = {};

    // stage K-tile k0 into buffer `buf`. LDS dest linear; global source slot-swizzled:
    // LDS slot (r, s) receives global 16B-chunk (s ^ (r&7)) of row r.
    auto STAGE = [&](int buf, int k0) {
#pragma unroll
        for (int is = 0; is < 4; ++is) {
            int idx16 = is * 256 + tid;                 // 0..1023
            int r     = idx16 >> 3;                     // row 0..127
            int s_swz = (idx16 ^ r) & 7;                // swizzled 16B chunk
            const __bf16* ga = Abf + (size_t)(rowBase + r) * K + k0 + s_swz * 8;
            __builtin_amdgcn_global_load_lds((AS1 void*)ga, (AS3 void*)(&As[buf][idx16 * 8]), 16, 0, 0);
            const __bf16* gb = Bbf + (size_t)(colBase + r) * K + k0 + s_swz * 8;
            __builtin_amdgcn_global_load_lds((AS1 void*)gb, (AS3 void*)(&Bs[buf][idx16 * 8]), 16, 0, 0);
        }
    };

    // compute one K-tile from buffer `buf`; frag read slot = linear slot ^ (row&7)
    auto COMPUTE = [&](int buf) {
#pragma unroll
        for (int kk = 0; kk < 2; ++kk) {
            bf16x8 af[4], bfr[4];
#pragma unroll
            for (int mi = 0; mi < 4; ++mi) {
                int row  = wr * 64 + mi * 16 + (lane & 15);
                int slot = (kk * 4 + (lane >> 4)) ^ (row & 7);
                af[mi] = *(const bf16x8*)(&As[buf][row * 64 + slot * 8]);
            }
#pragma unroll
            for (int ni = 0; ni < 4; ++ni) {
                int row  = wc * 64 + ni * 16 + (lane & 15);
                int slot = (kk * 4 + (lane >> 4)) ^ (row & 7);
                bfr[ni] = *(const bf16x8*)(&Bs[buf][row * 64 + slot * 8]);
            }
            __builtin_amdgcn_s_setprio(1);
#pragma unroll
            for (int mi = 0; mi < 4; ++mi)
#pragma unroll
                for (int ni = 0; ni < 4; ++ni)
                    acc[mi][ni] = __builtin_amdgcn_mfma_f32_16x16x32_bf16(
                        af[mi], bfr[ni], acc[mi][ni], 0, 0, 0);
            __builtin_amdgcn_s_setprio(0);
        }
    };

    // prologue: stage tile 0, drain, then pipelined loop
    STAGE(0, 0);
    __syncthreads();
#pragma unroll 1
    for (int t = 0; t < 15; ++t) {
        STAGE((t + 1) & 1, (t + 1) * 64);   // issue next-tile loads FIRST
        COMPUTE(t & 1);                      // MFMA hides the staging latency
        __syncthreads();                     // single drain per K-step
    }
    COMPUTE(1);                              // tile 15 (buf 1), no further stage

    // -------- fused epilogue --------
    const int b     = rowBase >> 11;            // uniform: 2048 % 128 == 0
    const int tTile = rowBase & 2047;
    const float* lab  = la  + (size_t)b * 2048;
    const float* qrow = qb2 + (size_t)b * 1024;

    float cw0[4], cw1[4], cw2[4], fv[4], qv[4];
#pragma unroll
    for (int ni = 0; ni < 4; ++ni) {
        int a = colBase + wc * 64 + ni * 16 + (lane & 15);
        cw0[ni] = convw[a * 3 + 0];
        cw1[ni] = convw[a * 3 + 1];
        cw2[ni] = convw[a * 3 + 2];
        fv[ni]  = fcw[a];
        qv[ni]  = qrow[a];
    }
    const int g4 = (lane >> 4) * 4;
#pragma unroll
    for (int mi = 0; mi < 4; ++mi) {
#pragma unroll
        for (int j = 0; j < 4; ++j) {
            int t = tTile + wr * 64 + mi * 16 + g4 + j;   // t within this b, [0,2048)
            float p1 = lab[t];
            float p0 = (t > 0)    ? lab[t - 1] : 0.f;     // SAME pad, per-b boundaries
            float p2 = (t < 2047) ? lab[t + 1] : 0.f;
            float sum = 0.f;
#pragma unroll
            for (int ni = 0; ni < 4; ++ni) {
                float e = acc[mi][ni][j] + qv[ni] + cw0[ni] * p0 + cw1[ni] * p1 + cw2[ni] * p2;
                // tanh(x) = 1 - 2/(1+e^{2x}); saturates correctly at +/-inf
                float h = 1.f - 2.f / (1.f + __expf(2.f * e));
                sum += fv[ni] * h;
            }
            // reduce over the 16 column-lanes (same output row)
            sum += __shfl_xor(sum, 1);
            sum += __shfl_xor(sum, 2);
            sum += __shfl_xor(sum, 4);
            sum += __shfl_xor(sum, 8);
            if ((lane & 15) == 0)
                ep_s[wr * 64 + mi * 16 + g4 + j][wc] = sum;
        }
    }
    __syncthreads();
    if (tid < 128) {
        float e = ep_s[tid][0] + ep_s[tid][1];
        ep[(size_t)ct * 65536 + rowBase + tid] = e;   // rowBase+tid == b*2048 + t
    }
}

// ---------------------------------------------------------------- softmax over T per batch row (sums 8 col-tile partials)
__global__ __launch_bounds__(256) void softmax_rows(const float* __restrict__ ep,
                                                    float* __restrict__ attn) {
    int b = blockIdx.x, tid = threadIdx.x;
    float* o = attn + (size_t)b * 2048;
    __shared__ float red[4], red2[4];

    float e8[8];
#pragma unroll
    for (int k = 0; k < 8; ++k) {
        int t = tid + 256 * k;
        float s = 0.f;
#pragma unroll
        for (int ct = 0; ct < 8; ++ct) s += ep[(size_t)ct * 65536 + b * 2048 + t];
        e8[k] = s;
    }

    float m = -1e30f;
#pragma unroll
    for (int k = 0; k < 8; ++k) m = fmaxf(m, e8[k]);
    for (int s = 1; s < 64; s <<= 1) m = fmaxf(m, __shfl_xor(m, s));
    if ((tid & 63) == 0) red[tid >> 6] = m;
    __syncthreads();
    m = fmaxf(fmaxf(red[0], red[1]), fmaxf(red[2], red[3]));

    float s = 0.f, vals[8];
#pragma unroll
    for (int k = 0; k < 8; ++k) { vals[k] = __expf(e8[k] - m); s += vals[k]; }
    for (int t = 1; t < 64; t <<= 1) s += __shfl_xor(s, t);
    if ((tid & 63) == 0) red2[tid >> 6] = s;
    __syncthreads();
    s = red2[0] + red2[1] + red2[2] + red2[3];
    float inv = 1.f / s;
#pragma unroll
    for (int k = 0; k < 8; ++k) o[tid + 256 * k] = vals[k] * inv;
}

// ---------------------------------------------------------------- context[b][d] = sum_t attn[b][t]*value[b][t][d]
__global__ __launch_bounds__(256) void context_kernel(const float* __restrict__ attn,
                                                      const __bf16* __restrict__ vbf,
                                                      float* __restrict__ ctx) {
    int b = blockIdx.x, tc = blockIdx.y, tid = threadIdx.x;
    int half = tid >> 7, dc = tid & 127;          // dc*8 .. dc*8+7 of D
    const float*  ab = attn + (size_t)b * 2048 + tc * 256 + half * 128;
    const __bf16* vb = vbf + ((size_t)(b * 2048 + tc * 256 + half * 128)) * 1024 + dc * 8;
    float c[8] = {};
#pragma unroll 4
    for (int t = 0; t < 128; ++t) {
        float  w = ab[t];
        bf16x8 v = *(const bf16x8*)(vb + (size_t)t * 1024);
#pragma unroll
        for (int k = 0; k < 8; ++k) c[k] += w * (float)v[k];
    }
    float* out = ctx + (size_t)b * 1024 + dc * 8;
#pragma unroll
    for (int k = 0; k < 8; ++k) atomicAdd(out + k, c[k]);
}

// ================================================================ host
extern "C" void kernel_launch(void* const* d_in, const int* in_sizes, int n_in,
                              void* d_out, int out_size, void* d_ws, size_t ws_size,
                              hipStream_t stream) {
    const float* query     = (const float*)d_in[0];
    const float* value     = (const float*)d_in[1];
    const float* last_attn = (const float*)d_in[2];
    const float* conv_w    = (const float*)d_in[3];
    const float* conv_b    = (const float*)d_in[4];
    const float* Wq        = (const float*)d_in[5];
    const float* Wv        = (const float*)d_in[6];
    const float* bias      = (const float*)d_in[7];
    const float* fc_w      = (const float*)d_in[8];
    // fc_b (d_in[9]) cancels in softmax

    float* ctx  = (float*)d_out;             // [32][1024]
    float* attn = (float*)d_out + 32 * 1024; // [32][2048]

    // workspace layout (ws is 1 GiB per harness poison)
    const size_t VBF_B  = (size_t)65536 * 1024 * 2;  // 128 MB full value in bf16
    const size_t WVBF_B = (size_t)1024 * 1024 * 2;   //   2 MB
    const size_t QB2_B  = (size_t)32 * 1024 * 4;     // 128 KB
    const size_t EP_B   = (size_t)8 * 32 * 2048 * 4; //   2 MB partial energies
    if (ws_size < VBF_B + WVBF_B + QB2_B + EP_B) return;  // loud failure, no OOB

    char*   ws   = (char*)d_ws;
    __bf16* vbf  = (__bf16*)ws;
    __bf16* wvbf = (__bf16*)(ws + VBF_B);
    float*  qb2  = (float*)(ws + VBF_B + WVBF_B);
    float*  ep   = (float*)(ws + VBF_B + WVBF_B + QB2_B);

    hipMemsetAsync(ctx, 0, 32 * 1024 * sizeof(float), stream);

    cast_bf16<<<512, 256, 0, stream>>>(Wv, wvbf, 1024 * 1024 / 8);
    prep_qb2<<<256, 256, 0, stream>>>(query, Wq, bias, conv_b, qb2);
    cast_bf16<<<32768, 256, 0, stream>>>(value, vbf, 65536 * 1024 / 8);

    gemm_fused<<<4096, 256, 0, stream>>>(vbf, wvbf, qb2, last_attn, conv_w, fc_w, ep);

    softmax_rows<<<32, 256, 0, stream>>>(ep, attn);
    dim3 gc(32, 8);
    context_kernel<<<gc, 256, 0, stream>>>(attn, vbf, ctx);
}

// Round 7
// 342.977 us; speedup vs baseline: 1.2777x; 1.1134x over previous
//
#include <hip/hip_runtime.h>
#include <stdint.h>

#define AS1 __attribute__((address_space(1)))
#define AS3 __attribute__((address_space(3)))

typedef __bf16 bf16x8 __attribute__((ext_vector_type(8)));
typedef float  f32x4  __attribute__((ext_vector_type(4)));

// ---------------------------------------------------------------- cast f32 -> bf16, 8 elems/thread
__global__ __launch_bounds__(256) void cast_bf16(const float* __restrict__ in,
                                                 __bf16* __restrict__ out, int n8) {
    int i = blockIdx.x * 256 + threadIdx.x;
    if (i >= n8) return;
    const float4* p = (const float4*)in + (size_t)i * 2;
    float4 x = p[0], y = p[1];
    bf16x8 v;
    v[0] = (__bf16)x.x; v[1] = (__bf16)x.y; v[2] = (__bf16)x.z; v[3] = (__bf16)x.w;
    v[4] = (__bf16)y.x; v[5] = (__bf16)y.y; v[6] = (__bf16)y.z; v[7] = (__bf16)y.w;
    *((bf16x8*)out + i) = v;
}

// ---------------------------------------------------------------- qb2[b][a] = q[b]·Wq[a] + bias[a] + conv_b[a]
__global__ __launch_bounds__(256) void prep_qb2(const float* __restrict__ q,
                                                const float* __restrict__ Wq,
                                                const float* __restrict__ bias,
                                                const float* __restrict__ convb,
                                                float* __restrict__ qb2) {
    int wid  = threadIdx.x >> 6;
    int lane = threadIdx.x & 63;
    int a    = blockIdx.x * 4 + wid;            // grid 256 blocks -> a in [0,1024)
    const float* wr_ = Wq + (size_t)a * 1024;
    float w[16];
#pragma unroll
    for (int j = 0; j < 16; ++j) w[j] = wr_[lane + 64 * j];
    float bb = bias[a] + convb[a];
    for (int b = 0; b < 32; ++b) {
        const float* qr = q + (size_t)b * 1024;
        float s = 0.f;
#pragma unroll
        for (int j = 0; j < 16; ++j) s += w[j] * qr[lane + 64 * j];
        for (int m = 1; m < 64; m <<= 1) s += __shfl_xor(s, m);
        if (lane == 0) qb2[b * 1024 + a] = s + bb;
    }
}

// ---------------------------------------------------------------- fused GEMM + loc-conv + tanh + fc reduce
// 256x256 tile, BK=64, 8 waves (2Mx4N), 512 threads, 128 KB LDS (1 block/CU).
// Per K-tile: STAGE(t+1) issued FIRST (latency hidden under ~2500cy of MFMA), then
// 4 compute sub-phases {4x ds_read A + 16 MFMA} with B-frags register-cached,
// ONE barrier per K-tile. T1 XCD swizzle + T2 LDS XOR swizzle + T5 setprio.
__global__ __launch_bounds__(512, 2) void gemm_fused(
    const __bf16* __restrict__ Abf,   // [65536][1024] bf16 value
    const __bf16* __restrict__ Bbf,   // [1024][1024] bf16 Wv
    const float*  __restrict__ qb2,   // [32][1024]  q·Wq + bias + conv_b
    const float*  __restrict__ la,    // [32][2048]  last_attn
    const float*  __restrict__ convw, // [1024][3]
    const float*  __restrict__ fcw,   // [1024]
    float* __restrict__ ep)           // [4][32][2048] partial energies per col-tile
{
    constexpr int K = 1024, NT = 16;
    __shared__ __bf16 As[2][256 * 64];   // 64 KB
    __shared__ __bf16 Bs[2][256 * 64];   // 64 KB

    const int tid  = threadIdx.x;
    const int lane = tid & 63;
    const int wid  = tid >> 6;           // 0..7
    const int wr   = wid >> 2, wc = wid & 3;   // 2 x 4 wave grid

    // T1 chunked XCD swizzle (nwg=1024, %8==0); ct fastest so A-panel sharers are adjacent.
    const int bid = blockIdx.x;
    const int swz = (bid & 7) * 128 + (bid >> 3);
    const int rt  = swz >> 2;                  // row tile 0..255
    const int ct  = swz & 3;                   // col tile 0..3
    const int rowBase = rt * 256;
    const int colBase = ct * 256;

    f32x4 acc[8][4] = {};

    // stage K-tile k0 into buffer buf. LDS dest linear (gload_lds requirement);
    // global source 16B-chunk swizzled s^(r&7); read side applies the same XOR.
    auto STAGE = [&](int buf, int k0) {
#pragma unroll
        for (int is = 0; is < 4; ++is) {
            int idx16 = is * 512 + tid;            // 0..2047
            int r     = idx16 >> 3;                // row 0..255
            int ssw   = (idx16 ^ r) & 7;           // swizzled 16B chunk within row
            const __bf16* ga = Abf + (size_t)(rowBase + r) * K + k0 + ssw * 8;
            __builtin_amdgcn_global_load_lds((AS1 void*)ga, (AS3 void*)(&As[buf][idx16 * 8]), 16, 0, 0);
            const __bf16* gb = Bbf + (size_t)(colBase + r) * K + k0 + ssw * 8;
            __builtin_amdgcn_global_load_lds((AS1 void*)gb, (AS3 void*)(&Bs[buf][idx16 * 8]), 16, 0, 0);
        }
    };

    auto COMPUTE = [&](int buf) {
        // B-frags once per K-tile, register-cached across both m-halves (8 ds_read)
        bf16x8 bfr[4][2];
#pragma unroll
        for (int ni = 0; ni < 4; ++ni)
#pragma unroll
            for (int kk = 0; kk < 2; ++kk) {
                int row  = wc * 64 + ni * 16 + (lane & 15);
                int slot = (kk * 4 + (lane >> 4)) ^ (row & 7);
                bfr[ni][kk] = *(const bf16x8*)(&Bs[buf][row * 64 + slot * 8]);
            }
        // 4 sub-phases: (m-half, kk) -> 4 A ds_read + 16 MFMA
#pragma unroll
        for (int mh = 0; mh < 2; ++mh)
#pragma unroll
            for (int kk = 0; kk < 2; ++kk) {
                bf16x8 af[4];
#pragma unroll
                for (int i = 0; i < 4; ++i) {
                    int row  = wr * 128 + (mh * 4 + i) * 16 + (lane & 15);
                    int slot = (kk * 4 + (lane >> 4)) ^ (row & 7);
                    af[i] = *(const bf16x8*)(&As[buf][row * 64 + slot * 8]);
                }
                __builtin_amdgcn_s_setprio(1);
#pragma unroll
                for (int i = 0; i < 4; ++i)
#pragma unroll
                    for (int ni = 0; ni < 4; ++ni)
                        acc[mh * 4 + i][ni] = __builtin_amdgcn_mfma_f32_16x16x32_bf16(
                            af[i], bfr[ni][kk], acc[mh * 4 + i][ni], 0, 0, 0);
                __builtin_amdgcn_s_setprio(0);
            }
    };

    STAGE(0, 0);
    __syncthreads();
#pragma unroll 1
    for (int t = 0; t < NT; ++t) {
        if (t + 1 < NT) STAGE((t + 1) & 1, (t + 1) * 64);  // prefetch first
        COMPUTE(t & 1);                                     // hides the staging latency
        __syncthreads();                                    // one drain+barrier per K-tile
    }

    // -------- fused epilogue --------
    const int b     = rowBase >> 11;            // uniform: 2048 % 256 == 0
    const int tTile = rowBase & 2047;
    const float* lab  = la  + (size_t)b * 2048;
    const float* qrow = qb2 + (size_t)b * 1024;

    float cw0[4], cw1[4], cw2[4], fv[4], qv[4];
#pragma unroll
    for (int ni = 0; ni < 4; ++ni) {
        int a = colBase + wc * 64 + ni * 16 + (lane & 15);
        cw0[ni] = convw[a * 3 + 0];
        cw1[ni] = convw[a * 3 + 1];
        cw2[ni] = convw[a * 3 + 2];
        fv[ni]  = fcw[a];
        qv[ni]  = qrow[a];
    }
    float* eps = (float*)&As[0][0];             // [256][4] scratch overlay (As[0] dead now)
    const int g4 = (lane >> 4) * 4;
#pragma unroll
    for (int mi = 0; mi < 8; ++mi) {
#pragma unroll
        for (int j = 0; j < 4; ++j) {
            int rloc = wr * 128 + mi * 16 + g4 + j;       // 0..255 within tile
            int t = tTile + rloc;                          // t within this b
            float p1 = lab[t];
            float p0 = (t > 0)    ? lab[t - 1] : 0.f;      // SAME pad, per-b boundaries
            float p2 = (t < 2047) ? lab[t + 1] : 0.f;
            float sum = 0.f;
#pragma unroll
            for (int ni = 0; ni < 4; ++ni) {
                float e = acc[mi][ni][j] + qv[ni] + cw0[ni] * p0 + cw1[ni] * p1 + cw2[ni] * p2;
                float h = 1.f - 2.f / (1.f + __expf(2.f * e));   // tanh
                sum += fv[ni] * h;
            }
            sum += __shfl_xor(sum, 1);
            sum += __shfl_xor(sum, 2);
            sum += __shfl_xor(sum, 4);
            sum += __shfl_xor(sum, 8);
            if ((lane & 15) == 0) eps[rloc * 4 + wc] = sum;
        }
    }
    __syncthreads();
    if (tid < 256) {
        float e = eps[tid * 4 + 0] + eps[tid * 4 + 1] + eps[tid * 4 + 2] + eps[tid * 4 + 3];
        ep[(size_t)ct * 65536 + rowBase + tid] = e;   // rowBase+tid == b*2048 + t
    }
}

// ---------------------------------------------------------------- softmax over T per batch row (sums 4 col-tile partials)
__global__ __launch_bounds__(256) void softmax_rows(const float* __restrict__ ep,
                                                    float* __restrict__ attn) {
    int b = blockIdx.x, tid = threadIdx.x;
    float* o = attn + (size_t)b * 2048;
    __shared__ float red[4], red2[4];

    float e8[8];
#pragma unroll
    for (int k = 0; k < 8; ++k) {
        int t = tid + 256 * k;
        float s = 0.f;
#pragma unroll
        for (int ct = 0; ct < 4; ++ct) s += ep[(size_t)ct * 65536 + b * 2048 + t];
        e8[k] = s;
    }

    float m = -1e30f;
#pragma unroll
    for (int k = 0; k < 8; ++k) m = fmaxf(m, e8[k]);
    for (int s = 1; s < 64; s <<= 1) m = fmaxf(m, __shfl_xor(m, s));
    if ((tid & 63) == 0) red[tid >> 6] = m;
    __syncthreads();
    m = fmaxf(fmaxf(red[0], red[1]), fmaxf(red[2], red[3]));

    float s = 0.f, vals[8];
#pragma unroll
    for (int k = 0; k < 8; ++k) { vals[k] = __expf(e8[k] - m); s += vals[k]; }
    for (int t = 1; t < 64; t <<= 1) s += __shfl_xor(s, t);
    if ((tid & 63) == 0) red2[tid >> 6] = s;
    __syncthreads();
    s = red2[0] + red2[1] + red2[2] + red2[3];
    float inv = 1.f / s;
#pragma unroll
    for (int k = 0; k < 8; ++k) o[tid + 256 * k] = vals[k] * inv;
}

// ---------------------------------------------------------------- context[b][d] = sum_t attn[b][t]*value[b][t][d]
__global__ __launch_bounds__(256) void context_kernel(const float* __restrict__ attn,
                                                      const __bf16* __restrict__ vbf,
                                                      float* __restrict__ ctx) {
    int b = blockIdx.x, tc = blockIdx.y, tid = threadIdx.x;
    int half = tid >> 7, dc = tid & 127;          // dc*8 .. dc*8+7 of D
    const float*  ab = attn + (size_t)b * 2048 + tc * 256 + half * 128;
    const __bf16* vb = vbf + ((size_t)(b * 2048 + tc * 256 + half * 128)) * 1024 + dc * 8;
    float c[8] = {};
#pragma unroll 4
    for (int t = 0; t < 128; ++t) {
        float  w = ab[t];
        bf16x8 v = *(const bf16x8*)(vb + (size_t)t * 1024);
#pragma unroll
        for (int k = 0; k < 8; ++k) c[k] += w * (float)v[k];
    }
    float* out = ctx + (size_t)b * 1024 + dc * 8;
#pragma unroll
    for (int k = 0; k < 8; ++k) atomicAdd(out + k, c[k]);
}

// ================================================================ host
extern "C" void kernel_launch(void* const* d_in, const int* in_sizes, int n_in,
                              void* d_out, int out_size, void* d_ws, size_t ws_size,
                              hipStream_t stream) {
    const float* query     = (const float*)d_in[0];
    const float* value     = (const float*)d_in[1];
    const float* last_attn = (const float*)d_in[2];
    const float* conv_w    = (const float*)d_in[3];
    const float* conv_b    = (const float*)d_in[4];
    const float* Wq        = (const float*)d_in[5];
    const float* Wv        = (const float*)d_in[6];
    const float* bias      = (const float*)d_in[7];
    const float* fc_w      = (const float*)d_in[8];
    // fc_b (d_in[9]) cancels in softmax

    float* ctx  = (float*)d_out;             // [32][1024]
    float* attn = (float*)d_out + 32 * 1024; // [32][2048]

    // workspace layout (ws is 1 GiB per harness poison)
    const size_t VBF_B  = (size_t)65536 * 1024 * 2;  // 128 MB full value in bf16
    const size_t WVBF_B = (size_t)1024 * 1024 * 2;   //   2 MB
    const size_t QB2_B  = (size_t)32 * 1024 * 4;     // 128 KB
    const size_t EP_B   = (size_t)4 * 32 * 2048 * 4; //   1 MB partial energies
    if (ws_size < VBF_B + WVBF_B + QB2_B + EP_B) return;  // loud failure, no OOB

    char*   ws   = (char*)d_ws;
    __bf16* vbf  = (__bf16*)ws;
    __bf16* wvbf = (__bf16*)(ws + VBF_B);
    float*  qb2  = (float*)(ws + VBF_B + WVBF_B);
    float*  ep   = (float*)(ws + VBF_B + WVBF_B + QB2_B);

    hipMemsetAsync(ctx, 0, 32 * 1024 * sizeof(float), stream);

    cast_bf16<<<512, 256, 0, stream>>>(Wv, wvbf, 1024 * 1024 / 8);
    prep_qb2<<<256, 256, 0, stream>>>(query, Wq, bias, conv_b, qb2);
    cast_bf16<<<32768, 256, 0, stream>>>(value, vbf, 65536 * 1024 / 8);

    gemm_fused<<<1024, 512, 0, stream>>>(vbf, wvbf, qb2, last_attn, conv_w, fc_w, ep);

    softmax_rows<<<32, 256, 0, stream>>>(ep, attn);
    dim3 gc(32, 8);
    context_kernel<<<gc, 256, 0, stream>>>(attn, vbf, ctx);
}

// Round 8
// 335.618 us; speedup vs baseline: 1.3057x; 1.0219x over previous
//
#include <hip/hip_runtime.h>
#include <stdint.h>

#define AS1 __attribute__((address_space(1)))
#define AS3 __attribute__((address_space(3)))

typedef __bf16 bf16x8 __attribute__((ext_vector_type(8)));
typedef float  f32x4  __attribute__((ext_vector_type(4)));

// ---------------------------------------------------------------- cast f32 -> bf16, 8 elems/thread
__global__ __launch_bounds__(256) void cast_bf16(const float* __restrict__ in,
                                                 __bf16* __restrict__ out, int n8) {
    int i = blockIdx.x * 256 + threadIdx.x;
    if (i >= n8) return;
    const float4* p = (const float4*)in + (size_t)i * 2;
    float4 x = p[0], y = p[1];
    bf16x8 v;
    v[0] = (__bf16)x.x; v[1] = (__bf16)x.y; v[2] = (__bf16)x.z; v[3] = (__bf16)x.w;
    v[4] = (__bf16)y.x; v[5] = (__bf16)y.y; v[6] = (__bf16)y.z; v[7] = (__bf16)y.w;
    *((bf16x8*)out + i) = v;
}

// ---------------------------------------------------------------- qb2[b][a] = q[b]·Wq[a] + bias[a] + conv_b[a]
__global__ __launch_bounds__(256) void prep_qb2(const float* __restrict__ q,
                                                const float* __restrict__ Wq,
                                                const float* __restrict__ bias,
                                                const float* __restrict__ convb,
                                                float* __restrict__ qb2) {
    int wid  = threadIdx.x >> 6;
    int lane = threadIdx.x & 63;
    int a    = blockIdx.x * 4 + wid;
    const float* wr_ = Wq + (size_t)a * 1024;
    float w[16];
#pragma unroll
    for (int j = 0; j < 16; ++j) w[j] = wr_[lane + 64 * j];
    float bb = bias[a] + convb[a];
    for (int b = 0; b < 32; ++b) {
        const float* qr = q + (size_t)b * 1024;
        float s = 0.f;
#pragma unroll
        for (int j = 0; j < 16; ++j) s += w[j] * qr[lane + 64 * j];
        for (int m = 1; m < 64; m <<= 1) s += __shfl_xor(s, m);
        if (lane == 0) qb2[b * 1024 + a] = s + bb;
    }
}

// ---------------------------------------------------------------- fused GEMM + loc-conv + tanh + fc reduce
// 256x256 tile, BK=64, 8 waves (2Mx4N), 512 threads, 128 KB LDS.
// T3+T4: 4 phases per K-tile {ds_read subtile | stage 1 half-tile | bar | lgkmcnt(0) |
// setprio+16 MFMA | bar}; ONE counted vmcnt(2) per K-tile (never 0 in main loop).
// T2 XOR swizzle (pre-swizzled global source + swizzled ds_read slot), T1 XCD swizzle.
__global__ __launch_bounds__(512, 2) void gemm_fused(
    const __bf16* __restrict__ Abf,   // [65536][1024] bf16 value
    const __bf16* __restrict__ Bbf,   // [1024][1024] bf16 Wv
    const float*  __restrict__ qb2,   // [32][1024]
    const float*  __restrict__ la,    // [32][2048]
    const float*  __restrict__ convw, // [1024][3]
    const float*  __restrict__ fcw,   // [1024]
    float* __restrict__ ep)           // [4][32][2048] partial energies per col-tile
{
    constexpr int K = 1024, NT = 16;
    __shared__ __bf16 As[2][256 * 64];   // 64 KB
    __shared__ __bf16 Bs[2][256 * 64];   // 64 KB

    const int tid  = threadIdx.x;
    const int lane = tid & 63;
    const int wid  = tid >> 6;
    const int wr   = wid >> 2, wc = wid & 3;   // 2 x 4 wave grid

    const int bid = blockIdx.x;                 // T1 chunked swizzle, nwg=1024 %8==0
    const int swz = (bid & 7) * 128 + (bid >> 3);
    const int rt  = swz >> 2;
    const int ct  = swz & 3;
    const int rowBase = rt * 256;
    const int colBase = ct * 256;

    f32x4 acc[8][4] = {};

    // stage one half-tile (128 rows x 64 K) = 2 x global_load_lds / thread.
    // LDS dest linear; global 16B-chunk source pre-swizzled s^(r&7) (rule #21 pair).
    auto STAGE_A = [&](int buf, int half, int k0) {
#pragma unroll
        for (int is = 0; is < 2; ++is) {
            int idx16 = half * 1024 + is * 512 + tid;
            int r     = idx16 >> 3;
            int ssw   = (idx16 ^ r) & 7;
            const __bf16* g = Abf + (size_t)(rowBase + r) * K + k0 + ssw * 8;
            __builtin_amdgcn_global_load_lds((AS1 void*)g, (AS3 void*)(&As[buf][idx16 * 8]), 16, 0, 0);
        }
    };
    auto STAGE_B = [&](int buf, int half, int k0) {
#pragma unroll
        for (int is = 0; is < 2; ++is) {
            int idx16 = half * 1024 + is * 512 + tid;
            int r     = idx16 >> 3;
            int ssw   = (idx16 ^ r) & 7;
            const __bf16* g = Bbf + (size_t)(colBase + r) * K + k0 + ssw * 8;
            __builtin_amdgcn_global_load_lds((AS1 void*)g, (AS3 void*)(&Bs[buf][idx16 * 8]), 16, 0, 0);
        }
    };

// one phase: optional B-frag reads, 4 A-frag reads, stage stmt, bar, lgkm0 (+fence, rule #18),
// setprio-wrapped 16 MFMA, bar.
#define DO_PHASE(bufv, kk, mh, READB, STAGE_STMT)                              \
    {                                                                          \
        if (READB) {                                                           \
            _Pragma("unroll")                                                  \
            for (int ni = 0; ni < 4; ++ni) {                                   \
                int row  = wc * 64 + ni * 16 + (lane & 15);                    \
                int slot = ((kk) * 4 + (lane >> 4)) ^ (row & 7);               \
                bfr[ni][kk] = *(const bf16x8*)(&Bs[bufv][row * 64 + slot * 8]);\
            }                                                                  \
        }                                                                      \
        bf16x8 af[4];                                                          \
        _Pragma("unroll")                                                      \
        for (int i = 0; i < 4; ++i) {                                          \
            int row  = wr * 128 + ((mh) * 4 + i) * 16 + (lane & 15);           \
            int slot = ((kk) * 4 + (lane >> 4)) ^ (row & 7);                   \
            af[i] = *(const bf16x8*)(&As[bufv][row * 64 + slot * 8]);          \
        }                                                                      \
        STAGE_STMT;                                                            \
        __builtin_amdgcn_s_barrier();                                          \
        asm volatile("s_waitcnt lgkmcnt(0)" ::: "memory");                     \
        __builtin_amdgcn_sched_barrier(0);                                     \
        __builtin_amdgcn_s_setprio(1);                                         \
        _Pragma("unroll")                                                      \
        for (int i = 0; i < 4; ++i)                                            \
            _Pragma("unroll")                                                  \
            for (int ni = 0; ni < 4; ++ni)                                     \
                acc[(mh) * 4 + i][ni] = __builtin_amdgcn_mfma_f32_16x16x32_bf16(\
                    af[i], bfr[ni][kk], acc[(mh) * 4 + i][ni], 0, 0, 0);       \
        __builtin_amdgcn_s_setprio(0);                                         \
        __builtin_amdgcn_s_barrier();                                          \
    }

    // prologue: all 4 halves of tile 0 into buf 0 (8 loads outstanding)
    STAGE_A(0, 0, 0); STAGE_A(0, 1, 0);
    STAGE_B(0, 0, 0); STAGE_B(0, 1, 0);

#pragma unroll 1
    for (int t = 0; t < NT - 1; ++t) {
        const int buf = t & 1;
        const int kn  = (t + 1) * 64;
        __builtin_amdgcn_sched_barrier(0);       // keep stages below prior barrier
        STAGE_A(buf ^ 1, 0, kn);                 // h0(t+1): issued before the wait
        __builtin_amdgcn_sched_barrier(0);
        asm volatile("s_waitcnt vmcnt(2)" ::: "memory");  // tile t fully in LDS; 2 in flight
        __builtin_amdgcn_s_barrier();            // bar_B: collective
        __builtin_amdgcn_sched_barrier(0);
        bf16x8 bfr[4][2];
        DO_PHASE(buf, 0, 0, true,  STAGE_A(buf ^ 1, 1, kn));
        DO_PHASE(buf, 0, 1, false, STAGE_B(buf ^ 1, 0, kn));
        DO_PHASE(buf, 1, 0, true,  STAGE_B(buf ^ 1, 1, kn));
        DO_PHASE(buf, 1, 1, false, (void)0);
    }
    {   // final tile (buf 1), no prefetch: the only vmcnt(0) drain
        asm volatile("s_waitcnt vmcnt(0)" ::: "memory");
        __builtin_amdgcn_s_barrier();
        __builtin_amdgcn_sched_barrier(0);
        bf16x8 bfr[4][2];
        DO_PHASE(1, 0, 0, true,  (void)0);
        DO_PHASE(1, 0, 1, false, (void)0);
        DO_PHASE(1, 1, 0, true,  (void)0);
        DO_PHASE(1, 1, 1, false, (void)0);
    }
#undef DO_PHASE

    // -------- fused epilogue --------
    const int b     = rowBase >> 11;            // uniform: 2048 % 256 == 0
    const int tTile = rowBase & 2047;
    const float* lab  = la  + (size_t)b * 2048;
    const float* qrow = qb2 + (size_t)b * 1024;

    float cw0[4], cw1[4], cw2[4], fv[4], qv[4];
#pragma unroll
    for (int ni = 0; ni < 4; ++ni) {
        int a = colBase + wc * 64 + ni * 16 + (lane & 15);
        cw0[ni] = convw[a * 3 + 0];
        cw1[ni] = convw[a * 3 + 1];
        cw2[ni] = convw[a * 3 + 2];
        fv[ni]  = fcw[a];
        qv[ni]  = qrow[a];
    }
    float* eps = (float*)&As[0][0];             // [256][4] scratch overlay (As dead now)
    const int g4 = (lane >> 4) * 4;
#pragma unroll
    for (int mi = 0; mi < 8; ++mi) {
#pragma unroll
        for (int j = 0; j < 4; ++j) {
            int rloc = wr * 128 + mi * 16 + g4 + j;       // 0..255 within tile
            int t = tTile + rloc;
            float p1 = lab[t];
            float p0 = (t > 0)    ? lab[t - 1] : 0.f;      // SAME pad, per-b boundaries
            float p2 = (t < 2047) ? lab[t + 1] : 0.f;
            float sum = 0.f;
#pragma unroll
            for (int ni = 0; ni < 4; ++ni) {
                float e = acc[mi][ni][j] + qv[ni] + cw0[ni] * p0 + cw1[ni] * p1 + cw2[ni] * p2;
                float h = 1.f - 2.f / (1.f + __expf(2.f * e));   // tanh
                sum += fv[ni] * h;
            }
            sum += __shfl_xor(sum, 1);
            sum += __shfl_xor(sum, 2);
            sum += __shfl_xor(sum, 4);
            sum += __shfl_xor(sum, 8);
            if ((lane & 15) == 0) eps[rloc * 4 + wc] = sum;
        }
    }
    __syncthreads();
    if (tid < 256) {
        float e = eps[tid * 4 + 0] + eps[tid * 4 + 1] + eps[tid * 4 + 2] + eps[tid * 4 + 3];
        ep[(size_t)ct * 65536 + rowBase + tid] = e;   // rowBase+tid == b*2048 + t
    }
}

// ---------------------------------------------------------------- softmax over T per batch row (sums 4 col-tile partials)
__global__ __launch_bounds__(256) void softmax_rows(const float* __restrict__ ep,
                                                    float* __restrict__ attn) {
    int b = blockIdx.x, tid = threadIdx.x;
    float* o = attn + (size_t)b * 2048;
    __shared__ float red[4], red2[4];

    float e8[8];
#pragma unroll
    for (int k = 0; k < 8; ++k) {
        int t = tid + 256 * k;
        float s = 0.f;
#pragma unroll
        for (int ct = 0; ct < 4; ++ct) s += ep[(size_t)ct * 65536 + b * 2048 + t];
        e8[k] = s;
    }

    float m = -1e30f;
#pragma unroll
    for (int k = 0; k < 8; ++k) m = fmaxf(m, e8[k]);
    for (int s = 1; s < 64; s <<= 1) m = fmaxf(m, __shfl_xor(m, s));
    if ((tid & 63) == 0) red[tid >> 6] = m;
    __syncthreads();
    m = fmaxf(fmaxf(red[0], red[1]), fmaxf(red[2], red[3]));

    float s = 0.f, vals[8];
#pragma unroll
    for (int k = 0; k < 8; ++k) { vals[k] = __expf(e8[k] - m); s += vals[k]; }
    for (int t = 1; t < 64; t <<= 1) s += __shfl_xor(s, t);
    if ((tid & 63) == 0) red2[tid >> 6] = s;
    __syncthreads();
    s = red2[0] + red2[1] + red2[2] + red2[3];
    float inv = 1.f / s;
#pragma unroll
    for (int k = 0; k < 8; ++k) o[tid + 256 * k] = vals[k] * inv;
}

// ---------------------------------------------------------------- context[b][d] = sum_t attn[b][t]*value[b][t][d]
__global__ __launch_bounds__(256) void context_kernel(const float* __restrict__ attn,
                                                      const __bf16* __restrict__ vbf,
                                                      float* __restrict__ ctx) {
    int b = blockIdx.x, tc = blockIdx.y, tid = threadIdx.x;
    int half = tid >> 7, dc = tid & 127;
    const float*  ab = attn + (size_t)b * 2048 + tc * 256 + half * 128;
    const __bf16* vb = vbf + ((size_t)(b * 2048 + tc * 256 + half * 128)) * 1024 + dc * 8;
    float c[8] = {};
#pragma unroll 4
    for (int t = 0; t < 128; ++t) {
        float  w = ab[t];
        bf16x8 v = *(const bf16x8*)(vb + (size_t)t * 1024);
#pragma unroll
        for (int k = 0; k < 8; ++k) c[k] += w * (float)v[k];
    }
    float* out = ctx + (size_t)b * 1024 + dc * 8;
#pragma unroll
    for (int k = 0; k < 8; ++k) atomicAdd(out + k, c[k]);
}

// ================================================================ host
extern "C" void kernel_launch(void* const* d_in, const int* in_sizes, int n_in,
                              void* d_out, int out_size, void* d_ws, size_t ws_size,
                              hipStream_t stream) {
    const float* query     = (const float*)d_in[0];
    const float* value     = (const float*)d_in[1];
    const float* last_attn = (const float*)d_in[2];
    const float* conv_w    = (const float*)d_in[3];
    const float* conv_b    = (const float*)d_in[4];
    const float* Wq        = (const float*)d_in[5];
    const float* Wv        = (const float*)d_in[6];
    const float* bias      = (const float*)d_in[7];
    const float* fc_w      = (const float*)d_in[8];
    // fc_b (d_in[9]) cancels in softmax

    float* ctx  = (float*)d_out;             // [32][1024]
    float* attn = (float*)d_out + 32 * 1024; // [32][2048]

    const size_t VBF_B  = (size_t)65536 * 1024 * 2;  // 128 MB full value in bf16
    const size_t WVBF_B = (size_t)1024 * 1024 * 2;   //   2 MB
    const size_t QB2_B  = (size_t)32 * 1024 * 4;     // 128 KB
    const size_t EP_B   = (size_t)4 * 32 * 2048 * 4; //   1 MB
    if (ws_size < VBF_B + WVBF_B + QB2_B + EP_B) return;

    char*   ws   = (char*)d_ws;
    __bf16* vbf  = (__bf16*)ws;
    __bf16* wvbf = (__bf16*)(ws + VBF_B);
    float*  qb2  = (float*)(ws + VBF_B + WVBF_B);
    float*  ep   = (float*)(ws + VBF_B + WVBF_B + QB2_B);

    hipMemsetAsync(ctx, 0, 32 * 1024 * sizeof(float), stream);

    cast_bf16<<<512, 256, 0, stream>>>(Wv, wvbf, 1024 * 1024 / 8);
    prep_qb2<<<256, 256, 0, stream>>>(query, Wq, bias, conv_b, qb2);
    cast_bf16<<<32768, 256, 0, stream>>>(value, vbf, 65536 * 1024 / 8);

    gemm_fused<<<1024, 512, 0, stream>>>(vbf, wvbf, qb2, last_attn, conv_w, fc_w, ep);

    softmax_rows<<<32, 256, 0, stream>>>(ep, attn);
    dim3 gc(32, 8);
    context_kernel<<<gc, 256, 0, stream>>>(attn, vbf, ctx);
}